// Round 13
// baseline (314.729 us; speedup 1.0000x reference)
//
#include <hip/hip_runtime.h>
#include <hip/hip_bf16.h>

#define T_ 128
#define N_ 1024
#define E_ 16384
#define D_ 256
#define H_ 8
#define D2_ 512    // 2*D
#define NB2_ 4096  // cell buckets: bucket = src*4 + (dst>>8), 256 cells each

typedef __attribute__((ext_vector_type(8))) short bf16x8;
typedef __attribute__((ext_vector_type(4))) float f32x4;

__device__ __forceinline__ void atomAddF(float* p, float v) {
#if defined(__HIP_PLATFORM_AMD__)
    unsafeAtomicAdd(p, v);
#else
    atomicAdd(p, v);
#endif
}

__device__ __forceinline__ unsigned short f2bf(float x) {
    return __bfloat16_as_ushort(__float2bfloat16(x));
}

// ---------------------------------------------------------------------------
// Kernel 1: k_prep — fused pool-zero + W1 bf16 fragment-cast + edge histogram.
// Histogram emitted as u8 cnt8[slot][bucket] (counts are ~Poisson(2), max ~15).
// ---------------------------------------------------------------------------
__global__ __launch_bounds__(256)
void k_prep(const float* __restrict__ W1, unsigned short* __restrict__ W1S,
            const int* __restrict__ edge_src, const int* __restrict__ edge_dst,
            float4* __restrict__ poolz, unsigned char* __restrict__ cnt8)
{
    __shared__ int hist[NB2_];
    const int bi = blockIdx.x, tid = threadIdx.x;
    const int s = bi >> 1, h = bi & 1;

    if (tid < 128) poolz[bi * 128 + tid] = make_float4(0.f, 0.f, 0.f, 0.f);

    if (tid < 64) {
        const int u   = bi * 64 + tid;
        const int col = u & 511;
        const int k8  = u >> 9;
        unsigned short hh[8];
        #pragma unroll
        for (int j = 0; j < 8; ++j)
            hh[j] = f2bf(W1[(size_t)(k8 * 8 + j) * D2_ + col]);
        uint4 pk;
        pk.x = hh[0] | ((unsigned)hh[1] << 16);
        pk.y = hh[2] | ((unsigned)hh[3] << 16);
        pk.z = hh[4] | ((unsigned)hh[5] << 16);
        pk.w = hh[6] | ((unsigned)hh[7] << 16);
        *(uint4*)&W1S[(size_t)k8 * 4096 + col * 8] = pk;
    }

    for (int i = tid; i < NB2_; i += 256) hist[i] = 0;
    __syncthreads();
    const int e0 = h * 8192;
    for (int e = e0 + tid; e < e0 + 8192; e += 256) {
        const size_t eo = (size_t)s * E_ + e;
        atomicAdd(&hist[(edge_src[eo] << 2) | (edge_dst[eo] >> 8)], 1);
    }
    __syncthreads();
    const int slot = (s << 1) | h;
    {
        const int b0 = tid * 16;
        uint w0 = (uint)hist[b0+0]  | ((uint)hist[b0+1]  << 8) |
                  ((uint)hist[b0+2]  << 16) | ((uint)hist[b0+3]  << 24);
        uint w1 = (uint)hist[b0+4]  | ((uint)hist[b0+5]  << 8) |
                  ((uint)hist[b0+6]  << 16) | ((uint)hist[b0+7]  << 24);
        uint w2 = (uint)hist[b0+8]  | ((uint)hist[b0+9]  << 8) |
                  ((uint)hist[b0+10] << 16) | ((uint)hist[b0+11] << 24);
        uint w3 = (uint)hist[b0+12] | ((uint)hist[b0+13] << 8) |
                  ((uint)hist[b0+14] << 16) | ((uint)hist[b0+15] << 24);
        *(uint4*)&cnt8[(size_t)slot * NB2_ + b0] = make_uint4(w0, w1, w2, w3);
    }
}

// ---------------------------------------------------------------------------
// Kernel 2: bf16 MFMA GEMM h = relu(emb@W1+b1), fused pooling.
// A-load for step ks+1 issued before the barrier (T14 issue-early hoist).
// ---------------------------------------------------------------------------
__global__ __launch_bounds__(512)
void k_mlp1_mfma(const float* __restrict__ emb,
                 const unsigned short* __restrict__ W1S,
                 const float* __restrict__ b1,
                 float* __restrict__ pool_sum,
                 unsigned int* __restrict__ pool_max)
{
    __shared__ unsigned short A_l[2048];   // [4 kb][64 row][8]  4 KB
    __shared__ unsigned short B_l[16384];  // [4 kb][512 col][8] 32 KB

    const int tid  = threadIdx.x;
    const int lane = tid & 63;
    const int wave = tid >> 6;
    const int wm = wave >> 2, wn = wave & 3;
    const int l15 = lane & 15, l4 = lane >> 4;
    const int r0 = blockIdx.x * 64;
    const int t  = blockIdx.x >> 4;

    f32x4 acc[2][8] = {};

    const int row = tid >> 3, k4 = tid & 7;
    const float* aptr = &emb[(size_t)(r0 + row) * D_ + k4 * 4];
    float4 curA = *(const float4*)aptr;

    for (int ks = 0; ks < 8; ++ks) {
        {
            uint2 pk;
            pk.x = f2bf(curA.x) | ((unsigned)f2bf(curA.y) << 16);
            pk.y = f2bf(curA.z) | ((unsigned)f2bf(curA.w) << 16);
            *(uint2*)&A_l[(k4 >> 1) * 512 + row * 8 + (k4 & 1) * 4] = pk;
        }
        {
            const char* gsrc = (const char*)W1S + (size_t)ks * 32768;
            #pragma unroll
            for (int r = 0; r < 4; ++r) {
                const int off = r * 8192 + tid * 16;
                __builtin_amdgcn_global_load_lds(
                    (const __attribute__((address_space(1))) unsigned int*)(gsrc + off),
                    (__attribute__((address_space(3))) unsigned int*)((char*)B_l + off),
                    16, 0, 0);
            }
        }
        float4 nextA = curA;
        if (ks < 7) nextA = *(const float4*)(aptr + (ks + 1) * 32);
        __syncthreads();

        const bf16x8 a0 = *(const bf16x8*)&A_l[l4 * 512 + (wm * 32 + l15) * 8];
        const bf16x8 a1 = *(const bf16x8*)&A_l[l4 * 512 + (wm * 32 + 16 + l15) * 8];
        #pragma unroll
        for (int cf = 0; cf < 8; ++cf) {
            const bf16x8 b = *(const bf16x8*)&B_l[l4 * 4096 + (wn * 128 + cf * 16 + l15) * 8];
            acc[0][cf] = __builtin_amdgcn_mfma_f32_16x16x32_bf16(a0, b, acc[0][cf], 0, 0, 0);
            acc[1][cf] = __builtin_amdgcn_mfma_f32_16x16x32_bf16(a1, b, acc[1][cf], 0, 0, 0);
        }
        __syncthreads();
        curA = nextA;
    }

    #pragma unroll
    for (int cf = 0; cf < 8; ++cf) {
        const int col = wn * 128 + cf * 16 + l15;
        const float bias = b1[col];
        float cs = 0.f, cm = 0.f;
        #pragma unroll
        for (int mf = 0; mf < 2; ++mf) {
            #pragma unroll
            for (int j = 0; j < 4; ++j) {
                float hh = acc[mf][cf][j] + bias;
                hh = fmaxf(hh, 0.f);
                cs += hh;
                cm = fmaxf(cm, hh);
            }
        }
        cs += __shfl_xor(cs, 16);
        cs += __shfl_xor(cs, 32);
        cm = fmaxf(cm, __shfl_xor(cm, 16));
        cm = fmaxf(cm, __shfl_xor(cm, 32));
        if (l4 == 0) {
            atomAddF(pool_sum + t * D2_ + col, cs);
            atomicMax(pool_max + t * D2_ + col, __float_as_uint(cm));
        }
    }
}

// ---------------------------------------------------------------------------
// Kernel 3: scatter edges -> bucket-major sortedC. grid 256 (2 per s).
// In-block scan over cnt8 replaces the old k_scan3 kernel: one coalesced
// uint4-per-row walk over 256 slots, 16 byte-lane buckets per thread;
// prefix captured at own slot + kc boundaries (block 0 emits segB).
// ---------------------------------------------------------------------------
__global__ __launch_bounds__(256)
void k_scatter3(const float* __restrict__ edge_val,
                const int* __restrict__ edge_src,
                const int* __restrict__ edge_dst,
                const unsigned char* __restrict__ cnt8,
                int* __restrict__ segB,
                uint2* __restrict__ sortedC)
{
    __shared__ int sc[256];
    __shared__ int bst[NB2_];   // 16 KB
    const int bi = blockIdx.x, tid = threadIdx.x;
    const int s = bi >> 1, h = bi & 1;
    const int slot = (s << 1) | h;

    int run[16] = {};
    int myPref[16];
    int kp[3][16];

    #pragma unroll
    for (int c = 0; c < 4; ++c) {
        if (c > 0) {
            #pragma unroll
            for (int j = 0; j < 16; ++j) kp[c - 1][j] = run[j];
        }
        #pragma unroll 4
        for (int r = c * 64; r < c * 64 + 64; ++r) {
            if (r == slot) {
                #pragma unroll
                for (int j = 0; j < 16; ++j) myPref[j] = run[j];
            }
            const uint4 w = *(const uint4*)&cnt8[(size_t)r * NB2_ + tid * 16];
            run[0]  += w.x & 255;          run[1]  += (w.x >> 8) & 255;
            run[2]  += (w.x >> 16) & 255;  run[3]  += w.x >> 24;
            run[4]  += w.y & 255;          run[5]  += (w.y >> 8) & 255;
            run[6]  += (w.y >> 16) & 255;  run[7]  += w.y >> 24;
            run[8]  += w.z & 255;          run[9]  += (w.z >> 8) & 255;
            run[10] += (w.z >> 16) & 255;  run[11] += w.z >> 24;
            run[12] += w.w & 255;          run[13] += (w.w >> 8) & 255;
            run[14] += (w.w >> 16) & 255;  run[15] += w.w >> 24;
        }
    }

    int tot = 0;
    #pragma unroll
    for (int j = 0; j < 16; ++j) tot += run[j];
    sc[tid] = tot;
    __syncthreads();
    #pragma unroll
    for (int off = 1; off < 256; off <<= 1) {
        int u = (tid >= off) ? sc[tid - off] : 0;
        __syncthreads();
        sc[tid] += u;
        __syncthreads();
    }
    int p = sc[tid] - tot;   // exclusive bucket-base for this thread's 16 buckets
    #pragma unroll
    for (int j = 0; j < 16; ++j) {
        const int i = tid * 16 + j;
        const int excl = p;
        p += run[j];
        if (bi == 0) {
            segB[i * 5 + 0] = excl;
            segB[i * 5 + 1] = excl + kp[0][j];
            segB[i * 5 + 2] = excl + kp[1][j];
            segB[i * 5 + 3] = excl + kp[2][j];
            segB[i * 5 + 4] = excl + run[j];
        }
        bst[i] = excl + myPref[j];
    }
    __syncthreads();

    const int e0 = h * 8192;
    for (int e = e0 + tid; e < e0 + 8192; e += 256) {
        const size_t eo = (size_t)s * E_ + e;
        const int src = edge_src[eo];
        const int dst = edge_dst[eo];
        const float vv = edge_val[eo];
        const int bkt = (src << 2) | (dst >> 8);
        const int gidx = atomicAdd(&bst[bkt], 1);
        sortedC[gidx] = make_uint2((unsigned)((s << 8) | (dst & 255)),
                                   __float_as_uint(vv));
    }
}

// ---------------------------------------------------------------------------
// Kernel 4: pooled -> x (LDS only) -> q,k
// ---------------------------------------------------------------------------
__global__ __launch_bounds__(256)
void k_mlp2qk(const float* __restrict__ pool_sum,
              const unsigned int* __restrict__ pool_max,
              const float* __restrict__ W2, const float* __restrict__ b2,
              const float* __restrict__ Wq, const float* __restrict__ bq,
              const float* __restrict__ Wk, const float* __restrict__ bk,
              float* __restrict__ q, float* __restrict__ k)
{
    __shared__ float pl[D2_];
    __shared__ float xl[D_];
    const int t = blockIdx.x;
    const int j = threadIdx.x;

    pl[j]       = pool_sum[t * D2_ + j]       * (1.0f / (float)N_) +
                  __uint_as_float(pool_max[t * D2_ + j]);
    pl[j + 256] = pool_sum[t * D2_ + j + 256] * (1.0f / (float)N_) +
                  __uint_as_float(pool_max[t * D2_ + j + 256]);
    __syncthreads();

    float acc = b2[j];
    for (int kk = 0; kk < D2_; ++kk)
        acc += pl[kk] * W2[(size_t)kk * D_ + j];
    acc = fmaxf(acc, 0.f);

    const int i2 = (j >> 1) * 2;
    const float div = expf((float)i2 * (-logf(10000.0f) / (float)D_));
    const float ang = (float)t * div;
    acc += (j & 1) ? cosf(ang) : sinf(ang);
    xl[j] = acc;
    __syncthreads();

    float aq = bq[j], ak = bk[j];
    for (int kk = 0; kk < D_; ++kk) {
        const float xv = xl[kk];
        aq += xv * Wq[(size_t)kk * D_ + j];
        ak += xv * Wk[(size_t)kk * D_ + j];
    }
    q[t * D_ + j] = aq * 0.17677669529663687f;  // (D/H)^-0.5
    k[t * D_ + j] = ak;
}

// ---------------------------------------------------------------------------
// Kernel 5: probs via wave-level reductions + fused Pfrag bf16 pack.
// ---------------------------------------------------------------------------
__global__ __launch_bounds__(128)
void k_probs(const float* __restrict__ q,
             const float* __restrict__ k,
             unsigned short* __restrict__ Pfrag)
{
    __shared__ float ql[D_];
    __shared__ float wmax[2][H_];
    __shared__ float wsum[2][H_];
    __shared__ float pall[T_];
    const int qt = blockIdx.x;
    const int kt = threadIdx.x;
    const int wv = kt >> 6, ln = kt & 63;

    ql[kt]       = q[qt * D_ + kt];
    ql[kt + 128] = q[qt * D_ + kt + 128];
    __syncthreads();

    float sh[H_];
    #pragma unroll
    for (int h = 0; h < H_; ++h) {
        float s = 0.f;
        #pragma unroll
        for (int d = 0; d < 32; ++d)
            s += ql[h * 32 + d] * k[kt * D_ + h * 32 + d];
        sh[h] = s;
    }

    #pragma unroll
    for (int h = 0; h < H_; ++h) {
        float v = sh[h];
        #pragma unroll
        for (int off = 32; off > 0; off >>= 1)
            v = fmaxf(v, __shfl_xor(v, off));
        if (ln == 0) wmax[wv][h] = v;
    }
    __syncthreads();
    float e[H_];
    #pragma unroll
    for (int h = 0; h < H_; ++h) {
        const float m = fmaxf(wmax[0][h], wmax[1][h]);
        e[h] = expf(sh[h] - m);
        float v = e[h];
        #pragma unroll
        for (int off = 32; off > 0; off >>= 1)
            v += __shfl_xor(v, off);
        if (ln == 0) wsum[wv][h] = v;
    }
    __syncthreads();
    float pm = 0.f;
    #pragma unroll
    for (int h = 0; h < H_; ++h)
        pm += e[h] / (wsum[0][h] + wsum[1][h]);
    pm *= (1.0f / (float)H_);

    if (pm < (1.0f / (float)T_)) pm = 0.f;
    if (kt == qt) pm += 1.0f;
    if (kt > qt) pm = 0.f;
    pall[kt] = pm;
    __syncthreads();

    if (kt < 16) {
        const int kc = kt >> 2, g = kt & 3;
        const int lane = g * 16 + (qt & 15);
        const int u = kc * 512 + (qt >> 4) * 64 + lane;
        const int s0 = kc * 32 + g * 8;
        unsigned short hh[8];
        #pragma unroll
        for (int j = 0; j < 8; ++j)
            hh[j] = f2bf(pall[s0 + j]);
        uint4 pk;
        pk.x = hh[0] | ((unsigned)hh[1] << 16);
        pk.y = hh[2] | ((unsigned)hh[3] << 16);
        pk.z = hh[4] | ((unsigned)hh[5] << 16);
        pk.w = hh[6] | ((unsigned)hh[7] << 16);
        *(uint4*)&Pfrag[u * 8] = pk;
    }
}

// ---------------------------------------------------------------------------
// Kernel 6: out[t][cell-tile] = P x A via MFMA, A built per s-chunk in LDS.
// Zero-fold: stage zeroed once up front; b-frag pass restores zeros after
// reading (read-then-write-0), removing the per-kc zero pass + 1 barrier.
// ---------------------------------------------------------------------------
__global__ __launch_bounds__(256)
void k_accum_mfma(const unsigned short* __restrict__ Pfrag,
                  const uint2* __restrict__ sortedC,
                  const int* __restrict__ segB,
                  float* __restrict__ out)
{
    __shared__ float stage[8576];           // kc-phase [32][258]; epi 2x[16][268]
    __shared__ unsigned short P_l[16384];   // 32 KB fragment-linear

    const int ct   = blockIdx.x;
    const int tid  = threadIdx.x;
    const int lane = tid & 63;
    const int wv   = tid >> 6;
    const int l15  = lane & 15, l4 = lane >> 4;

    #pragma unroll
    for (int r = 0; r < 8; ++r) {
        const int off = r * 4096 + tid * 16;
        __builtin_amdgcn_global_load_lds(
            (const __attribute__((address_space(1))) unsigned int*)((const char*)Pfrag + off),
            (__attribute__((address_space(3))) unsigned int*)((char*)P_l + off),
            16, 0, 0);
    }
    {   // one-time zero of the [32][258] region
        float4* s4 = (float4*)stage;
        for (int i = tid; i < 2064; i += 256)
            s4[i] = make_float4(0.f, 0.f, 0.f, 0.f);
    }

    const int sb = ct * 5;
    f32x4 acc[8][4] = {};   // [tf][cf]

    for (int kc = 0; kc < 4; ++kc) {
        __syncthreads();   // kc=0: zero+P_l done; kc>0: prev reads+re-zero done
        const int i0 = segB[sb + kc];
        const int i1 = segB[sb + kc + 1];
        for (int i = i0 + tid; i < i1; i += 256) {
            const uint2 it = sortedC[i];
            atomicAdd(&stage[((it.x >> 8) & 31) * 258 + (it.x & 255)],
                      __uint_as_float(it.y));
        }
        __syncthreads();

        #pragma unroll
        for (int cf = 0; cf < 4; ++cf) {
            const int c = wv * 64 + cf * 16 + l15;
            float bs[8];
            #pragma unroll
            for (int j = 0; j < 8; ++j) {
                const int idx = (l4 * 8 + j) * 258 + c;
                bs[j] = stage[idx];
                stage[idx] = 0.f;          // restore zero for next kc
            }
            bf16x8 bfr;
            #pragma unroll
            for (int j = 0; j < 8; ++j)
                bfr[j] = (short)f2bf(bs[j]);
            #pragma unroll
            for (int tf = 0; tf < 8; ++tf) {
                if (tf >= 2 * kc) {
                    const bf16x8 af =
                        *(const bf16x8*)&P_l[((kc * 8 + tf) * 64 + lane) * 8];
                    acc[tf][cf] = __builtin_amdgcn_mfma_f32_16x16x32_bf16(
                        af, bfr, acc[tf][cf], 0, 0, 0);
                }
            }
        }
    }

    // epilogue: 2 tf-slabs per barrier-pair, nontemporal 1KB-contiguous stores
    const int erow = tid >> 6;            // 0..3
    const int ecol = (tid & 63) * 4;      // float4 col
    #pragma unroll
    for (int tp = 0; tp < 4; ++tp) {
        __syncthreads();
        #pragma unroll
        for (int sl = 0; sl < 2; ++sl) {
            const int tf = tp * 2 + sl;
            #pragma unroll
            for (int cf = 0; cf < 4; ++cf) {
                const int c = wv * 64 + cf * 16 + l15;
                #pragma unroll
                for (int j = 0; j < 4; ++j)
                    stage[sl * 4288 + (l4 * 4 + j) * 268 + c] = acc[tf][cf][j];
            }
        }
        __syncthreads();
        #pragma unroll
        for (int sl = 0; sl < 2; ++sl) {
            const int tf = tp * 2 + sl;
            #pragma unroll
            for (int ii = 0; ii < 4; ++ii) {
                const int row = ii * 4 + erow;
                const f32x4 vv = *(const f32x4*)&stage[sl * 4288 + row * 268 + ecol];
                __builtin_nontemporal_store(vv,
                    (f32x4*)&out[((size_t)(tf * 16 + row) << 20) + ct * 256 + ecol]);
            }
        }
    }
}

// ---------------------------------------------------------------------------
extern "C" void kernel_launch(void* const* d_in, const int* in_sizes, int n_in,
                              void* d_out, int out_size, void* d_ws, size_t ws_size,
                              hipStream_t stream) {
    const float* emb      = (const float*)d_in[0];
    const float* W1       = (const float*)d_in[1];
    const float* b1       = (const float*)d_in[2];
    const float* W2       = (const float*)d_in[3];
    const float* b2       = (const float*)d_in[4];
    const float* Wq       = (const float*)d_in[5];
    const float* bq       = (const float*)d_in[6];
    const float* Wk       = (const float*)d_in[7];
    const float* bk       = (const float*)d_in[8];
    const float* edge_val = (const float*)d_in[9];
    const int*   edge_src = (const int*)d_in[10];
    const int*   edge_dst = (const int*)d_in[11];
    float* out = (float*)d_out;

    char* ws = (char*)d_ws;
    float*          pool_sum = (float*)(ws);                         // 256 KB
    unsigned int*   pool_max = (unsigned int*)(ws + (256 << 10));    // 256 KB
    float*          q        = (float*)(ws + (512 << 10));           // 128 KB
    float*          k        = (float*)(ws + (640 << 10));           // 128 KB
    unsigned short* W1S      = (unsigned short*)(ws + (832 << 10));  // 256 KB
    unsigned short* Pfrag    = (unsigned short*)(ws + (1088 << 10)); // 32 KB
    int*            segB     = (int*)(ws + (1136 << 10));            // 80 KB
    unsigned char*  cnt8     = (unsigned char*)(ws + (1216 << 10));  // 1 MB
    uint2*          sortedC  = (uint2*)(ws + (3328 << 10));          // 16 MB

    k_prep<<<256, 256, 0, stream>>>(W1, W1S, edge_src, edge_dst,
                                    (float4*)pool_sum, cnt8);
    k_mlp1_mfma<<<2048, 512, 0, stream>>>(emb, W1S, b1, pool_sum, pool_max);
    k_scatter3<<<256, 256, 0, stream>>>(edge_val, edge_src, edge_dst,
                                        cnt8, segB, sortedC);
    k_mlp2qk<<<128, 256, 0, stream>>>(pool_sum, pool_max, W2, b2,
                                      Wq, bq, Wk, bk, q, k);
    k_probs<<<128, 128, 0, stream>>>(q, k, Pfrag);
    k_accum_mfma<<<NB2_, 256, 0, stream>>>(Pfrag, sortedC, segB, out);
}

// Round 14
// 301.068 us; speedup vs baseline: 1.0454x; 1.0454x over previous
//
#include <hip/hip_runtime.h>
#include <hip/hip_bf16.h>

#define T_ 128
#define N_ 1024
#define E_ 16384
#define D_ 256
#define H_ 8
#define D2_ 512    // 2*D
#define NB2_ 4096  // cell buckets: bucket = src*4 + (dst>>8), 256 cells each
#define PS3_ 257   // prefS3 row stride (256 (s,half) slots + 1)

typedef __attribute__((ext_vector_type(8))) short bf16x8;
typedef __attribute__((ext_vector_type(4))) float f32x4;

__device__ __forceinline__ void atomAddF(float* p, float v) {
#if defined(__HIP_PLATFORM_AMD__)
    unsafeAtomicAdd(p, v);
#else
    atomicAdd(p, v);
#endif
}

__device__ __forceinline__ unsigned short f2bf(float x) {
    return __bfloat16_as_ushort(__float2bfloat16(x));
}

// ---------------------------------------------------------------------------
// Kernel 1: k_prep — fused pool-zero + W1 bf16 fragment-cast + edge histogram.
// ---------------------------------------------------------------------------
__global__ __launch_bounds__(256)
void k_prep(const float* __restrict__ W1, unsigned short* __restrict__ W1S,
            const int* __restrict__ edge_src, const int* __restrict__ edge_dst,
            float4* __restrict__ poolz, int* __restrict__ cnt)
{
    __shared__ int hist[NB2_];
    const int bi = blockIdx.x, tid = threadIdx.x;
    const int s = bi >> 1, h = bi & 1;

    if (tid < 128) poolz[bi * 128 + tid] = make_float4(0.f, 0.f, 0.f, 0.f);

    if (tid < 64) {
        const int u   = bi * 64 + tid;
        const int col = u & 511;
        const int k8  = u >> 9;
        unsigned short hh[8];
        #pragma unroll
        for (int j = 0; j < 8; ++j)
            hh[j] = f2bf(W1[(size_t)(k8 * 8 + j) * D2_ + col]);
        uint4 pk;
        pk.x = hh[0] | ((unsigned)hh[1] << 16);
        pk.y = hh[2] | ((unsigned)hh[3] << 16);
        pk.z = hh[4] | ((unsigned)hh[5] << 16);
        pk.w = hh[6] | ((unsigned)hh[7] << 16);
        *(uint4*)&W1S[(size_t)k8 * 4096 + col * 8] = pk;
    }

    for (int i = tid; i < NB2_; i += 256) hist[i] = 0;
    __syncthreads();
    const int e0 = h * 8192;
    for (int e = e0 + tid; e < e0 + 8192; e += 256) {
        const size_t eo = (size_t)s * E_ + e;
        atomicAdd(&hist[(edge_src[eo] << 2) | (edge_dst[eo] >> 8)], 1);
    }
    __syncthreads();
    const int slot = (s << 1) | h;
    for (int i = tid; i < NB2_; i += 256) cnt[i * 256 + slot] = hist[i];
}

// ---------------------------------------------------------------------------
// Kernel 2: bf16 MFMA GEMM h = relu(emb@W1+b1), fused pooling. (r12 proven)
// ---------------------------------------------------------------------------
__global__ __launch_bounds__(512)
void k_mlp1_mfma(const float* __restrict__ emb,
                 const unsigned short* __restrict__ W1S,
                 const float* __restrict__ b1,
                 float* __restrict__ pool_sum,
                 unsigned int* __restrict__ pool_max)
{
    __shared__ unsigned short A_l[2048];   // [4 kb][64 row][8]  4 KB
    __shared__ unsigned short B_l[16384];  // [4 kb][512 col][8] 32 KB

    const int tid  = threadIdx.x;
    const int lane = tid & 63;
    const int wave = tid >> 6;
    const int wm = wave >> 2, wn = wave & 3;
    const int l15 = lane & 15, l4 = lane >> 4;
    const int r0 = blockIdx.x * 64;
    const int t  = blockIdx.x >> 4;

    f32x4 acc[2][8] = {};

    for (int ks = 0; ks < 8; ++ks) {
        {
            const int row = tid >> 3, k4 = tid & 7;
            const float4 v = *(const float4*)&emb[(size_t)(r0 + row) * D_ + ks * 32 + k4 * 4];
            uint2 pk;
            pk.x = f2bf(v.x) | ((unsigned)f2bf(v.y) << 16);
            pk.y = f2bf(v.z) | ((unsigned)f2bf(v.w) << 16);
            *(uint2*)&A_l[(k4 >> 1) * 512 + row * 8 + (k4 & 1) * 4] = pk;
        }
        {
            const char* gsrc = (const char*)W1S + (size_t)ks * 32768;
            #pragma unroll
            for (int r = 0; r < 4; ++r) {
                const int off = r * 8192 + tid * 16;
                __builtin_amdgcn_global_load_lds(
                    (const __attribute__((address_space(1))) unsigned int*)(gsrc + off),
                    (__attribute__((address_space(3))) unsigned int*)((char*)B_l + off),
                    16, 0, 0);
            }
        }
        __syncthreads();

        const bf16x8 a0 = *(const bf16x8*)&A_l[l4 * 512 + (wm * 32 + l15) * 8];
        const bf16x8 a1 = *(const bf16x8*)&A_l[l4 * 512 + (wm * 32 + 16 + l15) * 8];
        #pragma unroll
        for (int cf = 0; cf < 8; ++cf) {
            const bf16x8 b = *(const bf16x8*)&B_l[l4 * 4096 + (wn * 128 + cf * 16 + l15) * 8];
            acc[0][cf] = __builtin_amdgcn_mfma_f32_16x16x32_bf16(a0, b, acc[0][cf], 0, 0, 0);
            acc[1][cf] = __builtin_amdgcn_mfma_f32_16x16x32_bf16(a1, b, acc[1][cf], 0, 0, 0);
        }
        __syncthreads();
    }

    #pragma unroll
    for (int cf = 0; cf < 8; ++cf) {
        const int col = wn * 128 + cf * 16 + l15;
        const float bias = b1[col];
        float cs = 0.f, cm = 0.f;
        #pragma unroll
        for (int mf = 0; mf < 2; ++mf) {
            #pragma unroll
            for (int j = 0; j < 4; ++j) {
                float hh = acc[mf][cf][j] + bias;
                hh = fmaxf(hh, 0.f);
                cs += hh;
                cm = fmaxf(cm, hh);
            }
        }
        cs += __shfl_xor(cs, 16);
        cs += __shfl_xor(cs, 32);
        cm = fmaxf(cm, __shfl_xor(cm, 16));
        cm = fmaxf(cm, __shfl_xor(cm, 32));
        if (l4 == 0) {
            atomAddF(pool_sum + t * D2_ + col, cs);
            atomicMax(pool_max + t * D2_ + col, __float_as_uint(cm));
        }
    }
}

// ---------------------------------------------------------------------------
// Kernel 3: per-bucket scan over 256 (s,half) slots. (r12 proven)
// ---------------------------------------------------------------------------
__global__ __launch_bounds__(256)
void k_scan3(const int* __restrict__ cnt, unsigned short* __restrict__ prefS3,
             int* __restrict__ totB)
{
    __shared__ int sc[256];
    const int b = blockIdx.x, tid = threadIdx.x;
    sc[tid] = cnt[b * 256 + tid];
    __syncthreads();
    #pragma unroll
    for (int off = 1; off < 256; off <<= 1) {
        int v = (tid >= off) ? sc[tid - off] : 0;
        __syncthreads();
        sc[tid] += v;
        __syncthreads();
    }
    prefS3[b * PS3_ + tid + 1] = (unsigned short)sc[tid];
    if (tid == 0)   prefS3[b * PS3_] = 0;
    if (tid == 255) totB[b] = sc[255];
}

// ---------------------------------------------------------------------------
// Kernel 4: scatter edges -> bucket-major sortedC. (r12 proven)
// ---------------------------------------------------------------------------
__global__ __launch_bounds__(256)
void k_scatter3(const float* __restrict__ edge_val,
                const int* __restrict__ edge_src,
                const int* __restrict__ edge_dst,
                const unsigned short* __restrict__ prefS3,
                const int* __restrict__ totB,
                int* __restrict__ segB,
                uint2* __restrict__ sortedC)
{
    __shared__ int sc[256];
    __shared__ int bst[NB2_];   // 16 KB
    const int bi = blockIdx.x, tid = threadIdx.x;
    const int s = bi >> 1, h = bi & 1;
    const int slot = (s << 1) | h;

    int v[16];
    int run = 0;
    const int4* t4 = (const int4*)&totB[tid * 16];
    #pragma unroll
    for (int r4 = 0; r4 < 4; ++r4) {
        const int4 x = t4[r4];
        v[r4 * 4 + 0] = x.x; v[r4 * 4 + 1] = x.y;
        v[r4 * 4 + 2] = x.z; v[r4 * 4 + 3] = x.w;
        run += x.x + x.y + x.z + x.w;
    }
    sc[tid] = run;
    __syncthreads();
    #pragma unroll
    for (int off = 1; off < 256; off <<= 1) {
        int u = (tid >= off) ? sc[tid - off] : 0;
        __syncthreads();
        sc[tid] += u;
        __syncthreads();
    }
    int p = sc[tid] - run;
    #pragma unroll
    for (int r = 0; r < 16; ++r) {
        const int i = tid * 16 + r;
        const int excl = p;
        p += v[r];
        if (bi == 0) {
            #pragma unroll
            for (int kcx = 0; kcx < 5; ++kcx)
                segB[i * 5 + kcx] = excl + (int)prefS3[i * PS3_ + kcx * 64];
        }
        bst[i] = excl + (int)prefS3[i * PS3_ + slot];
    }
    __syncthreads();

    const int e0 = h * 8192;
    for (int e = e0 + tid; e < e0 + 8192; e += 256) {
        const size_t eo = (size_t)s * E_ + e;
        const int src = edge_src[eo];
        const int dst = edge_dst[eo];
        const float vv = edge_val[eo];
        const int bkt = (src << 2) | (dst >> 8);
        const int gidx = atomicAdd(&bst[bkt], 1);
        sortedC[gidx] = make_uint2((unsigned)((s << 8) | (dst & 255)),
                                   __float_as_uint(vv));
    }
}

// ---------------------------------------------------------------------------
// Kernel 5: pooled -> x (LDS only) -> q,k
// ---------------------------------------------------------------------------
__global__ __launch_bounds__(256)
void k_mlp2qk(const float* __restrict__ pool_sum,
              const unsigned int* __restrict__ pool_max,
              const float* __restrict__ W2, const float* __restrict__ b2,
              const float* __restrict__ Wq, const float* __restrict__ bq,
              const float* __restrict__ Wk, const float* __restrict__ bk,
              float* __restrict__ q, float* __restrict__ k)
{
    __shared__ float pl[D2_];
    __shared__ float xl[D_];
    const int t = blockIdx.x;
    const int j = threadIdx.x;

    pl[j]       = pool_sum[t * D2_ + j]       * (1.0f / (float)N_) +
                  __uint_as_float(pool_max[t * D2_ + j]);
    pl[j + 256] = pool_sum[t * D2_ + j + 256] * (1.0f / (float)N_) +
                  __uint_as_float(pool_max[t * D2_ + j + 256]);
    __syncthreads();

    float acc = b2[j];
    for (int kk = 0; kk < D2_; ++kk)
        acc += pl[kk] * W2[(size_t)kk * D_ + j];
    acc = fmaxf(acc, 0.f);

    const int i2 = (j >> 1) * 2;
    const float div = expf((float)i2 * (-logf(10000.0f) / (float)D_));
    const float ang = (float)t * div;
    acc += (j & 1) ? cosf(ang) : sinf(ang);
    xl[j] = acc;
    __syncthreads();

    float aq = bq[j], ak = bk[j];
    for (int kk = 0; kk < D_; ++kk) {
        const float xv = xl[kk];
        aq += xv * Wq[(size_t)kk * D_ + j];
        ak += xv * Wk[(size_t)kk * D_ + j];
    }
    q[t * D_ + j] = aq * 0.17677669529663687f;  // (D/H)^-0.5
    k[t * D_ + j] = ak;
}

// ---------------------------------------------------------------------------
// Kernel 6: probs via wave-level reductions + fused Pfrag bf16 pack.
// ---------------------------------------------------------------------------
__global__ __launch_bounds__(128)
void k_probs(const float* __restrict__ q,
             const float* __restrict__ k,
             unsigned short* __restrict__ Pfrag)
{
    __shared__ float ql[D_];
    __shared__ float wmax[2][H_];
    __shared__ float wsum[2][H_];
    __shared__ float pall[T_];
    const int qt = blockIdx.x;
    const int kt = threadIdx.x;
    const int wv = kt >> 6, ln = kt & 63;

    ql[kt]       = q[qt * D_ + kt];
    ql[kt + 128] = q[qt * D_ + kt + 128];
    __syncthreads();

    float sh[H_];
    #pragma unroll
    for (int h = 0; h < H_; ++h) {
        float s = 0.f;
        #pragma unroll
        for (int d = 0; d < 32; ++d)
            s += ql[h * 32 + d] * k[kt * D_ + h * 32 + d];
        sh[h] = s;
    }

    #pragma unroll
    for (int h = 0; h < H_; ++h) {
        float v = sh[h];
        #pragma unroll
        for (int off = 32; off > 0; off >>= 1)
            v = fmaxf(v, __shfl_xor(v, off));
        if (ln == 0) wmax[wv][h] = v;
    }
    __syncthreads();
    float e[H_];
    #pragma unroll
    for (int h = 0; h < H_; ++h) {
        const float m = fmaxf(wmax[0][h], wmax[1][h]);
        e[h] = expf(sh[h] - m);
        float v = e[h];
        #pragma unroll
        for (int off = 32; off > 0; off >>= 1)
            v += __shfl_xor(v, off);
        if (ln == 0) wsum[wv][h] = v;
    }
    __syncthreads();
    float pm = 0.f;
    #pragma unroll
    for (int h = 0; h < H_; ++h)
        pm += e[h] / (wsum[0][h] + wsum[1][h]);
    pm *= (1.0f / (float)H_);

    if (pm < (1.0f / (float)T_)) pm = 0.f;
    if (kt == qt) pm += 1.0f;
    if (kt > qt) pm = 0.f;
    pall[kt] = pm;
    __syncthreads();

    if (kt < 16) {
        const int kc = kt >> 2, g = kt & 3;
        const int lane = g * 16 + (qt & 15);
        const int u = kc * 512 + (qt >> 4) * 64 + lane;
        const int s0 = kc * 32 + g * 8;
        unsigned short hh[8];
        #pragma unroll
        for (int j = 0; j < 8; ++j)
            hh[j] = f2bf(pall[s0 + j]);
        uint4 pk;
        pk.x = hh[0] | ((unsigned)hh[1] << 16);
        pk.y = hh[2] | ((unsigned)hh[3] << 16);
        pk.z = hh[4] | ((unsigned)hh[5] << 16);
        pk.w = hh[6] | ((unsigned)hh[7] << 16);
        *(uint4*)&Pfrag[u * 8] = pk;
    }
}

// ---------------------------------------------------------------------------
// Kernel 7: out[t][cell-tile] = P x A via MFMA — 8-WAVE version.
// 512 thr = 8 waves: wave = (whalf = tf-half) x (wq = col-quad).
// acc[4][4] = 64 VGPR/thread (was 128) -> 4 waves/SIMD bracket; staging and
// zero passes spread over 512 threads. MFMA/barrier structure unchanged.
// ---------------------------------------------------------------------------
__global__ __launch_bounds__(512)
void k_accum_mfma(const unsigned short* __restrict__ Pfrag,
                  const uint2* __restrict__ sortedC,
                  const int* __restrict__ segB,
                  float* __restrict__ out)
{
    __shared__ float stage[8576];           // kc-phase [32][258]; epi 2x[16][268]
    __shared__ unsigned short P_l[16384];   // 32 KB fragment-linear

    const int ct    = blockIdx.x;
    const int tid   = threadIdx.x;
    const int lane  = tid & 63;
    const int wv    = tid >> 6;        // 0..7
    const int whalf = wv >> 2;         // tf half: tf = whalf*4 + tfi
    const int wq    = wv & 3;          // col quad (64 cols)
    const int l15   = lane & 15, l4 = lane >> 4;

    #pragma unroll
    for (int r = 0; r < 4; ++r) {
        const int off = r * 8192 + tid * 16;
        __builtin_amdgcn_global_load_lds(
            (const __attribute__((address_space(1))) unsigned int*)((const char*)Pfrag + off),
            (__attribute__((address_space(3))) unsigned int*)((char*)P_l + off),
            16, 0, 0);
    }

    const int sb = ct * 5;
    f32x4 acc[4][4] = {};   // [tfi][cf]

    for (int kc = 0; kc < 4; ++kc) {
        __syncthreads();
        {   // zero [32][258]: 2064 float4 over 512 threads
            float4* s4 = (float4*)stage;
            for (int i = tid; i < 2064; i += 512)
                s4[i] = make_float4(0.f, 0.f, 0.f, 0.f);
        }
        __syncthreads();
        const int i0 = segB[sb + kc];
        const int i1 = segB[sb + kc + 1];
        for (int i = i0 + tid; i < i1; i += 512) {
            const uint2 it = sortedC[i];
            atomicAdd(&stage[((it.x >> 8) & 31) * 258 + (it.x & 255)],
                      __uint_as_float(it.y));
        }
        __syncthreads();

        #pragma unroll
        for (int cf = 0; cf < 4; ++cf) {
            const int c = wq * 64 + cf * 16 + l15;
            float bs[8];
            #pragma unroll
            for (int j = 0; j < 8; ++j)
                bs[j] = stage[(l4 * 8 + j) * 258 + c];
            bf16x8 bfr;
            #pragma unroll
            for (int j = 0; j < 8; ++j)
                bfr[j] = (short)f2bf(bs[j]);
            #pragma unroll
            for (int tfi = 0; tfi < 4; ++tfi) {
                const int tf = whalf * 4 + tfi;
                if (tf >= 2 * kc) {    // wave-uniform triangular skip
                    const bf16x8 af =
                        *(const bf16x8*)&P_l[((kc * 8 + tf) * 64 + lane) * 8];
                    acc[tfi][cf] = __builtin_amdgcn_mfma_f32_16x16x32_bf16(
                        af, bfr, acc[tfi][cf], 0, 0, 0);
                }
            }
        }
    }

    // epilogue: 2 tf-slabs per barrier-pair; owner-half writes, all store
    #pragma unroll
    for (int tp = 0; tp < 4; ++tp) {
        __syncthreads();
        #pragma unroll
        for (int sl = 0; sl < 2; ++sl) {
            const int tf = tp * 2 + sl;
            if ((tf >> 2) == whalf) {
                const int tfi = tf & 3;
                #pragma unroll
                for (int cf = 0; cf < 4; ++cf) {
                    const int c = wq * 64 + cf * 16 + l15;
                    #pragma unroll
                    for (int j = 0; j < 4; ++j)
                        stage[sl * 4288 + (l4 * 4 + j) * 268 + c] = acc[tfi][cf][j];
                }
            }
        }
        __syncthreads();
        #pragma unroll
        for (int ii = 0; ii < 4; ++ii) {
            const int u = ii * 512 + tid;       // 0..2047
            const int sl = u >> 10;             // slab
            const int row = (u >> 6) & 15;
            const int c4 = (u & 63) * 4;
            const int tf = tp * 2 + sl;
            const f32x4 vv = *(const f32x4*)&stage[sl * 4288 + row * 268 + c4];
            __builtin_nontemporal_store(vv,
                (f32x4*)&out[((size_t)(tf * 16 + row) << 20) + ct * 256 + c4]);
        }
    }
}

// ---------------------------------------------------------------------------
extern "C" void kernel_launch(void* const* d_in, const int* in_sizes, int n_in,
                              void* d_out, int out_size, void* d_ws, size_t ws_size,
                              hipStream_t stream) {
    const float* emb      = (const float*)d_in[0];
    const float* W1       = (const float*)d_in[1];
    const float* b1       = (const float*)d_in[2];
    const float* W2       = (const float*)d_in[3];
    const float* b2       = (const float*)d_in[4];
    const float* Wq       = (const float*)d_in[5];
    const float* bq       = (const float*)d_in[6];
    const float* Wk       = (const float*)d_in[7];
    const float* bk       = (const float*)d_in[8];
    const float* edge_val = (const float*)d_in[9];
    const int*   edge_src = (const int*)d_in[10];
    const int*   edge_dst = (const int*)d_in[11];
    float* out = (float*)d_out;

    char* ws = (char*)d_ws;
    float*          pool_sum = (float*)(ws);                         // 256 KB
    unsigned int*   pool_max = (unsigned int*)(ws + (256 << 10));    // 256 KB
    float*          q        = (float*)(ws + (512 << 10));           // 128 KB
    float*          k        = (float*)(ws + (640 << 10));           // 128 KB
    unsigned short* W1S      = (unsigned short*)(ws + (832 << 10));  // 256 KB
    unsigned short* Pfrag    = (unsigned short*)(ws + (1088 << 10)); // 32 KB
    int*            totB     = (int*)(ws + (1120 << 10));            // 16 KB
    int*            segB     = (int*)(ws + (1136 << 10));            // 80 KB
    unsigned short* prefS3   = (unsigned short*)(ws + (1216 << 10)); // ~2056 KB
    int*            cnt      = (int*)(ws + (3328 << 10));            // 4 MB (aliased)
    uint2*          sortedC  = (uint2*)(ws + (3328 << 10));          // 16 MB

    k_prep<<<256, 256, 0, stream>>>(W1, W1S, edge_src, edge_dst,
                                    (float4*)pool_sum, cnt);
    k_mlp1_mfma<<<2048, 512, 0, stream>>>(emb, W1S, b1, pool_sum, pool_max);
    k_scan3<<<NB2_, 256, 0, stream>>>(cnt, prefS3, totB);
    k_scatter3<<<256, 256, 0, stream>>>(edge_val, edge_src, edge_dst,
                                        prefS3, totB, segB, sortedC);
    k_mlp2qk<<<128, 256, 0, stream>>>(pool_sum, pool_max, W2, b2,
                                      Wq, bq, Wk, bk, q, k);
    k_probs<<<128, 128, 0, stream>>>(q, k, Pfrag);
    k_accum_mfma<<<NB2_, 512, 0, stream>>>(Pfrag, sortedC, segB, out);
}

// Round 15
// 292.419 us; speedup vs baseline: 1.0763x; 1.0296x over previous
//
#include <hip/hip_runtime.h>
#include <hip/hip_bf16.h>

#define T_ 128
#define N_ 1024
#define E_ 16384
#define D_ 256
#define H_ 8
#define D2_ 512    // 2*D
#define NB2_ 4096  // cell buckets: bucket = src*4 + (dst>>8), 256 cells each
#define PS3_ 257   // prefS3 row stride (256 (s,half) slots + 1)

typedef __attribute__((ext_vector_type(8))) short bf16x8;
typedef __attribute__((ext_vector_type(4))) float f32x4;

__device__ __forceinline__ void atomAddF(float* p, float v) {
#if defined(__HIP_PLATFORM_AMD__)
    unsafeAtomicAdd(p, v);
#else
    atomicAdd(p, v);
#endif
}

__device__ __forceinline__ unsigned short f2bf(float x) {
    return __bfloat16_as_ushort(__float2bfloat16(x));
}

// ---------------------------------------------------------------------------
// Kernel 1: k_prep — fused pool-zero + W1 bf16 fragment-cast + edge histogram.
// ---------------------------------------------------------------------------
__global__ __launch_bounds__(256)
void k_prep(const float* __restrict__ W1, unsigned short* __restrict__ W1S,
            const int* __restrict__ edge_src, const int* __restrict__ edge_dst,
            float4* __restrict__ poolz, int* __restrict__ cnt)
{
    __shared__ int hist[NB2_];
    const int bi = blockIdx.x, tid = threadIdx.x;
    const int s = bi >> 1, h = bi & 1;

    if (tid < 128) poolz[bi * 128 + tid] = make_float4(0.f, 0.f, 0.f, 0.f);

    if (tid < 64) {
        const int u   = bi * 64 + tid;
        const int col = u & 511;
        const int k8  = u >> 9;
        unsigned short hh[8];
        #pragma unroll
        for (int j = 0; j < 8; ++j)
            hh[j] = f2bf(W1[(size_t)(k8 * 8 + j) * D2_ + col]);
        uint4 pk;
        pk.x = hh[0] | ((unsigned)hh[1] << 16);
        pk.y = hh[2] | ((unsigned)hh[3] << 16);
        pk.z = hh[4] | ((unsigned)hh[5] << 16);
        pk.w = hh[6] | ((unsigned)hh[7] << 16);
        *(uint4*)&W1S[(size_t)k8 * 4096 + col * 8] = pk;
    }

    for (int i = tid; i < NB2_; i += 256) hist[i] = 0;
    __syncthreads();
    const int e0 = h * 8192;
    for (int e = e0 + tid; e < e0 + 8192; e += 256) {
        const size_t eo = (size_t)s * E_ + e;
        atomicAdd(&hist[(edge_src[eo] << 2) | (edge_dst[eo] >> 8)], 1);
    }
    __syncthreads();
    const int slot = (s << 1) | h;
    for (int i = tid; i < NB2_; i += 256) cnt[i * 256 + slot] = hist[i];
}

// ---------------------------------------------------------------------------
// Kernel 2: bf16 MFMA GEMM h = relu(emb@W1+b1), fused pooling. (r12 proven)
// ---------------------------------------------------------------------------
__global__ __launch_bounds__(512)
void k_mlp1_mfma(const float* __restrict__ emb,
                 const unsigned short* __restrict__ W1S,
                 const float* __restrict__ b1,
                 float* __restrict__ pool_sum,
                 unsigned int* __restrict__ pool_max)
{
    __shared__ unsigned short A_l[2048];   // [4 kb][64 row][8]  4 KB
    __shared__ unsigned short B_l[16384];  // [4 kb][512 col][8] 32 KB

    const int tid  = threadIdx.x;
    const int lane = tid & 63;
    const int wave = tid >> 6;
    const int wm = wave >> 2, wn = wave & 3;
    const int l15 = lane & 15, l4 = lane >> 4;
    const int r0 = blockIdx.x * 64;
    const int t  = blockIdx.x >> 4;

    f32x4 acc[2][8] = {};

    for (int ks = 0; ks < 8; ++ks) {
        {
            const int row = tid >> 3, k4 = tid & 7;
            const float4 v = *(const float4*)&emb[(size_t)(r0 + row) * D_ + ks * 32 + k4 * 4];
            uint2 pk;
            pk.x = f2bf(v.x) | ((unsigned)f2bf(v.y) << 16);
            pk.y = f2bf(v.z) | ((unsigned)f2bf(v.w) << 16);
            *(uint2*)&A_l[(k4 >> 1) * 512 + row * 8 + (k4 & 1) * 4] = pk;
        }
        {
            const char* gsrc = (const char*)W1S + (size_t)ks * 32768;
            #pragma unroll
            for (int r = 0; r < 4; ++r) {
                const int off = r * 8192 + tid * 16;
                __builtin_amdgcn_global_load_lds(
                    (const __attribute__((address_space(1))) unsigned int*)(gsrc + off),
                    (__attribute__((address_space(3))) unsigned int*)((char*)B_l + off),
                    16, 0, 0);
            }
        }
        __syncthreads();

        const bf16x8 a0 = *(const bf16x8*)&A_l[l4 * 512 + (wm * 32 + l15) * 8];
        const bf16x8 a1 = *(const bf16x8*)&A_l[l4 * 512 + (wm * 32 + 16 + l15) * 8];
        #pragma unroll
        for (int cf = 0; cf < 8; ++cf) {
            const bf16x8 b = *(const bf16x8*)&B_l[l4 * 4096 + (wn * 128 + cf * 16 + l15) * 8];
            acc[0][cf] = __builtin_amdgcn_mfma_f32_16x16x32_bf16(a0, b, acc[0][cf], 0, 0, 0);
            acc[1][cf] = __builtin_amdgcn_mfma_f32_16x16x32_bf16(a1, b, acc[1][cf], 0, 0, 0);
        }
        __syncthreads();
    }

    #pragma unroll
    for (int cf = 0; cf < 8; ++cf) {
        const int col = wn * 128 + cf * 16 + l15;
        const float bias = b1[col];
        float cs = 0.f, cm = 0.f;
        #pragma unroll
        for (int mf = 0; mf < 2; ++mf) {
            #pragma unroll
            for (int j = 0; j < 4; ++j) {
                float hh = acc[mf][cf][j] + bias;
                hh = fmaxf(hh, 0.f);
                cs += hh;
                cm = fmaxf(cm, hh);
            }
        }
        cs += __shfl_xor(cs, 16);
        cs += __shfl_xor(cs, 32);
        cm = fmaxf(cm, __shfl_xor(cm, 16));
        cm = fmaxf(cm, __shfl_xor(cm, 32));
        if (l4 == 0) {
            atomAddF(pool_sum + t * D2_ + col, cs);
            atomicMax(pool_max + t * D2_ + col, __float_as_uint(cm));
        }
    }
}

// ---------------------------------------------------------------------------
// Kernel 3: per-bucket scan over 256 (s,half) slots. (r12 proven)
// ---------------------------------------------------------------------------
__global__ __launch_bounds__(256)
void k_scan3(const int* __restrict__ cnt, unsigned short* __restrict__ prefS3,
             int* __restrict__ totB)
{
    __shared__ int sc[256];
    const int b = blockIdx.x, tid = threadIdx.x;
    sc[tid] = cnt[b * 256 + tid];
    __syncthreads();
    #pragma unroll
    for (int off = 1; off < 256; off <<= 1) {
        int v = (tid >= off) ? sc[tid - off] : 0;
        __syncthreads();
        sc[tid] += v;
        __syncthreads();
    }
    prefS3[b * PS3_ + tid + 1] = (unsigned short)sc[tid];
    if (tid == 0)   prefS3[b * PS3_] = 0;
    if (tid == 255) totB[b] = sc[255];
}

// ---------------------------------------------------------------------------
// Kernel 4: scatter edges -> bucket-major sortedC. (r12 proven)
// ---------------------------------------------------------------------------
__global__ __launch_bounds__(256)
void k_scatter3(const float* __restrict__ edge_val,
                const int* __restrict__ edge_src,
                const int* __restrict__ edge_dst,
                const unsigned short* __restrict__ prefS3,
                const int* __restrict__ totB,
                int* __restrict__ segB,
                uint2* __restrict__ sortedC)
{
    __shared__ int sc[256];
    __shared__ int bst[NB2_];   // 16 KB
    const int bi = blockIdx.x, tid = threadIdx.x;
    const int s = bi >> 1, h = bi & 1;
    const int slot = (s << 1) | h;

    int v[16];
    int run = 0;
    const int4* t4 = (const int4*)&totB[tid * 16];
    #pragma unroll
    for (int r4 = 0; r4 < 4; ++r4) {
        const int4 x = t4[r4];
        v[r4 * 4 + 0] = x.x; v[r4 * 4 + 1] = x.y;
        v[r4 * 4 + 2] = x.z; v[r4 * 4 + 3] = x.w;
        run += x.x + x.y + x.z + x.w;
    }
    sc[tid] = run;
    __syncthreads();
    #pragma unroll
    for (int off = 1; off < 256; off <<= 1) {
        int u = (tid >= off) ? sc[tid - off] : 0;
        __syncthreads();
        sc[tid] += u;
        __syncthreads();
    }
    int p = sc[tid] - run;
    #pragma unroll
    for (int r = 0; r < 16; ++r) {
        const int i = tid * 16 + r;
        const int excl = p;
        p += v[r];
        if (bi == 0) {
            #pragma unroll
            for (int kcx = 0; kcx < 5; ++kcx)
                segB[i * 5 + kcx] = excl + (int)prefS3[i * PS3_ + kcx * 64];
        }
        bst[i] = excl + (int)prefS3[i * PS3_ + slot];
    }
    __syncthreads();

    const int e0 = h * 8192;
    for (int e = e0 + tid; e < e0 + 8192; e += 256) {
        const size_t eo = (size_t)s * E_ + e;
        const int src = edge_src[eo];
        const int dst = edge_dst[eo];
        const float vv = edge_val[eo];
        const int bkt = (src << 2) | (dst >> 8);
        const int gidx = atomicAdd(&bst[bkt], 1);
        sortedC[gidx] = make_uint2((unsigned)((s << 8) | (dst & 255)),
                                   __float_as_uint(vv));
    }
}

// ---------------------------------------------------------------------------
// Kernel 5: pooled -> x (LDS only) -> q,k
// ---------------------------------------------------------------------------
__global__ __launch_bounds__(256)
void k_mlp2qk(const float* __restrict__ pool_sum,
              const unsigned int* __restrict__ pool_max,
              const float* __restrict__ W2, const float* __restrict__ b2,
              const float* __restrict__ Wq, const float* __restrict__ bq,
              const float* __restrict__ Wk, const float* __restrict__ bk,
              float* __restrict__ q, float* __restrict__ k)
{
    __shared__ float pl[D2_];
    __shared__ float xl[D_];
    const int t = blockIdx.x;
    const int j = threadIdx.x;

    pl[j]       = pool_sum[t * D2_ + j]       * (1.0f / (float)N_) +
                  __uint_as_float(pool_max[t * D2_ + j]);
    pl[j + 256] = pool_sum[t * D2_ + j + 256] * (1.0f / (float)N_) +
                  __uint_as_float(pool_max[t * D2_ + j + 256]);
    __syncthreads();

    float acc = b2[j];
    for (int kk = 0; kk < D2_; ++kk)
        acc += pl[kk] * W2[(size_t)kk * D_ + j];
    acc = fmaxf(acc, 0.f);

    const int i2 = (j >> 1) * 2;
    const float div = expf((float)i2 * (-logf(10000.0f) / (float)D_));
    const float ang = (float)t * div;
    acc += (j & 1) ? cosf(ang) : sinf(ang);
    xl[j] = acc;
    __syncthreads();

    float aq = bq[j], ak = bk[j];
    for (int kk = 0; kk < D_; ++kk) {
        const float xv = xl[kk];
        aq += xv * Wq[(size_t)kk * D_ + j];
        ak += xv * Wk[(size_t)kk * D_ + j];
    }
    q[t * D_ + j] = aq * 0.17677669529663687f;  // (D/H)^-0.5
    k[t * D_ + j] = ak;
}

// ---------------------------------------------------------------------------
// Kernel 6: probs via wave-level reductions + fused Pfrag bf16 pack.
// ---------------------------------------------------------------------------
__global__ __launch_bounds__(128)
void k_probs(const float* __restrict__ q,
             const float* __restrict__ k,
             unsigned short* __restrict__ Pfrag)
{
    __shared__ float ql[D_];
    __shared__ float wmax[2][H_];
    __shared__ float wsum[2][H_];
    __shared__ float pall[T_];
    const int qt = blockIdx.x;
    const int kt = threadIdx.x;
    const int wv = kt >> 6, ln = kt & 63;

    ql[kt]       = q[qt * D_ + kt];
    ql[kt + 128] = q[qt * D_ + kt + 128];
    __syncthreads();

    float sh[H_];
    #pragma unroll
    for (int h = 0; h < H_; ++h) {
        float s = 0.f;
        #pragma unroll
        for (int d = 0; d < 32; ++d)
            s += ql[h * 32 + d] * k[kt * D_ + h * 32 + d];
        sh[h] = s;
    }

    #pragma unroll
    for (int h = 0; h < H_; ++h) {
        float v = sh[h];
        #pragma unroll
        for (int off = 32; off > 0; off >>= 1)
            v = fmaxf(v, __shfl_xor(v, off));
        if (ln == 0) wmax[wv][h] = v;
    }
    __syncthreads();
    float e[H_];
    #pragma unroll
    for (int h = 0; h < H_; ++h) {
        const float m = fmaxf(wmax[0][h], wmax[1][h]);
        e[h] = expf(sh[h] - m);
        float v = e[h];
        #pragma unroll
        for (int off = 32; off > 0; off >>= 1)
            v += __shfl_xor(v, off);
        if (ln == 0) wsum[wv][h] = v;
    }
    __syncthreads();
    float pm = 0.f;
    #pragma unroll
    for (int h = 0; h < H_; ++h)
        pm += e[h] / (wsum[0][h] + wsum[1][h]);
    pm *= (1.0f / (float)H_);

    if (pm < (1.0f / (float)T_)) pm = 0.f;
    if (kt == qt) pm += 1.0f;
    if (kt > qt) pm = 0.f;
    pall[kt] = pm;
    __syncthreads();

    if (kt < 16) {
        const int kc = kt >> 2, g = kt & 3;
        const int lane = g * 16 + (qt & 15);
        const int u = kc * 512 + (qt >> 4) * 64 + lane;
        const int s0 = kc * 32 + g * 8;
        unsigned short hh[8];
        #pragma unroll
        for (int j = 0; j < 8; ++j)
            hh[j] = f2bf(pall[s0 + j]);
        uint4 pk;
        pk.x = hh[0] | ((unsigned)hh[1] << 16);
        pk.y = hh[2] | ((unsigned)hh[3] << 16);
        pk.z = hh[4] | ((unsigned)hh[5] << 16);
        pk.w = hh[6] | ((unsigned)hh[7] << 16);
        *(uint4*)&Pfrag[u * 8] = pk;
    }
}

// ---------------------------------------------------------------------------
// Kernel 7: out[t][cell-tile] = P x A via MFMA, A built per s-chunk in LDS.
// (r12 proven: 256 threads, per-kc zero pass, nt-store epilogue)
// ---------------------------------------------------------------------------
__global__ __launch_bounds__(256)
void k_accum_mfma(const unsigned short* __restrict__ Pfrag,
                  const uint2* __restrict__ sortedC,
                  const int* __restrict__ segB,
                  float* __restrict__ out)
{
    __shared__ float stage[8576];           // kc-phase [32][258]; epi 2x[16][268]
    __shared__ unsigned short P_l[16384];   // 32 KB fragment-linear

    const int ct   = blockIdx.x;
    const int tid  = threadIdx.x;
    const int lane = tid & 63;
    const int wv   = tid >> 6;
    const int l15  = lane & 15, l4 = lane >> 4;

    #pragma unroll
    for (int r = 0; r < 8; ++r) {
        const int off = r * 4096 + tid * 16;
        __builtin_amdgcn_global_load_lds(
            (const __attribute__((address_space(1))) unsigned int*)((const char*)Pfrag + off),
            (__attribute__((address_space(3))) unsigned int*)((char*)P_l + off),
            16, 0, 0);
    }

    const int sb = ct * 5;
    f32x4 acc[8][4] = {};   // [tf][cf]

    for (int kc = 0; kc < 4; ++kc) {
        __syncthreads();
        {
            float4* s4 = (float4*)stage;
            for (int i = tid; i < 2064; i += 256)
                s4[i] = make_float4(0.f, 0.f, 0.f, 0.f);
        }
        __syncthreads();
        const int i0 = segB[sb + kc];
        const int i1 = segB[sb + kc + 1];
        for (int i = i0 + tid; i < i1; i += 256) {
            const uint2 it = sortedC[i];
            atomicAdd(&stage[((it.x >> 8) & 31) * 258 + (it.x & 255)],
                      __uint_as_float(it.y));
        }
        __syncthreads();

        #pragma unroll
        for (int cf = 0; cf < 4; ++cf) {
            const int c = wv * 64 + cf * 16 + l15;
            float bs[8];
            #pragma unroll
            for (int j = 0; j < 8; ++j)
                bs[j] = stage[(l4 * 8 + j) * 258 + c];
            bf16x8 bfr;
            #pragma unroll
            for (int j = 0; j < 8; ++j)
                bfr[j] = (short)f2bf(bs[j]);
            #pragma unroll
            for (int tf = 0; tf < 8; ++tf) {
                if (tf >= 2 * kc) {
                    const bf16x8 af =
                        *(const bf16x8*)&P_l[((kc * 8 + tf) * 64 + lane) * 8];
                    acc[tf][cf] = __builtin_amdgcn_mfma_f32_16x16x32_bf16(
                        af, bfr, acc[tf][cf], 0, 0, 0);
                }
            }
        }
    }

    // epilogue: 2 tf-slabs per barrier-pair, nontemporal 1KB-contiguous stores
    const int erow = tid >> 6;            // 0..3
    const int ecol = (tid & 63) * 4;      // float4 col
    #pragma unroll
    for (int tp = 0; tp < 4; ++tp) {
        __syncthreads();
        #pragma unroll
        for (int sl = 0; sl < 2; ++sl) {
            const int tf = tp * 2 + sl;
            #pragma unroll
            for (int cf = 0; cf < 4; ++cf) {
                const int c = wv * 64 + cf * 16 + l15;
                #pragma unroll
                for (int j = 0; j < 4; ++j)
                    stage[sl * 4288 + (l4 * 4 + j) * 268 + c] = acc[tf][cf][j];
            }
        }
        __syncthreads();
        #pragma unroll
        for (int sl = 0; sl < 2; ++sl) {
            const int tf = tp * 2 + sl;
            #pragma unroll
            for (int ii = 0; ii < 4; ++ii) {
                const int row = ii * 4 + erow;
                const f32x4 vv = *(const f32x4*)&stage[sl * 4288 + row * 268 + ecol];
                __builtin_nontemporal_store(vv,
                    (f32x4*)&out[((size_t)(tf * 16 + row) << 20) + ct * 256 + ecol]);
            }
        }
    }
}

// ---------------------------------------------------------------------------
extern "C" void kernel_launch(void* const* d_in, const int* in_sizes, int n_in,
                              void* d_out, int out_size, void* d_ws, size_t ws_size,
                              hipStream_t stream) {
    const float* emb      = (const float*)d_in[0];
    const float* W1       = (const float*)d_in[1];
    const float* b1       = (const float*)d_in[2];
    const float* W2       = (const float*)d_in[3];
    const float* b2       = (const float*)d_in[4];
    const float* Wq       = (const float*)d_in[5];
    const float* bq       = (const float*)d_in[6];
    const float* Wk       = (const float*)d_in[7];
    const float* bk       = (const float*)d_in[8];
    const float* edge_val = (const float*)d_in[9];
    const int*   edge_src = (const int*)d_in[10];
    const int*   edge_dst = (const int*)d_in[11];
    float* out = (float*)d_out;

    char* ws = (char*)d_ws;
    float*          pool_sum = (float*)(ws);                         // 256 KB
    unsigned int*   pool_max = (unsigned int*)(ws + (256 << 10));    // 256 KB
    float*          q        = (float*)(ws + (512 << 10));           // 128 KB
    float*          k        = (float*)(ws + (640 << 10));           // 128 KB
    unsigned short* W1S      = (unsigned short*)(ws + (832 << 10));  // 256 KB
    unsigned short* Pfrag    = (unsigned short*)(ws + (1088 << 10)); // 32 KB
    int*            totB     = (int*)(ws + (1120 << 10));            // 16 KB
    int*            segB     = (int*)(ws + (1136 << 10));            // 80 KB
    unsigned short* prefS3   = (unsigned short*)(ws + (1216 << 10)); // ~2056 KB
    int*            cnt      = (int*)(ws + (3328 << 10));            // 4 MB (aliased)
    uint2*          sortedC  = (uint2*)(ws + (3328 << 10));          // 16 MB

    k_prep<<<256, 256, 0, stream>>>(W1, W1S, edge_src, edge_dst,
                                    (float4*)pool_sum, cnt);
    k_mlp1_mfma<<<2048, 512, 0, stream>>>(emb, W1S, b1, pool_sum, pool_max);
    k_scan3<<<NB2_, 256, 0, stream>>>(cnt, prefS3, totB);
    k_scatter3<<<256, 256, 0, stream>>>(edge_val, edge_src, edge_dst,
                                        prefS3, totB, segB, sortedC);
    k_mlp2qk<<<128, 256, 0, stream>>>(pool_sum, pool_max, W2, b2,
                                      Wq, bq, Wk, bk, q, k);
    k_probs<<<128, 128, 0, stream>>>(q, k, Pfrag);
    k_accum_mfma<<<NB2_, 256, 0, stream>>>(Pfrag, sortedC, segB, out);
}